// Round 1
// baseline (128.668 us; speedup 1.0000x reference)
//
#include <hip/hip_runtime.h>

// Problem constants (fixed by setup_inputs):
//   B=64, O=100, A=9 anchors total (3 per layer)
//   layers: (128,128,3) (64,64,3) (32,32,3)
//   slots/layer: 49152, 12288, 3072  -> NSLOT = 64512 per batch
// Output (flat f32, concatenated in return order):
//   xcyc [B,NSLOT,2] | wh [B,NSLOT,2] | obj [B,NSLOT] | cls [B,NSLOT] | wt [B,NSLOT,2]

namespace {
constexpr int B = 64;
constexpr int O = 100;
constexpr int A = 9;
constexpr int NSLOT = 49152 + 12288 + 3072;               // 64512
constexpr long long BASE_XCYC = 0;
constexpr long long BASE_WH   = (long long)B * NSLOT * 2; // 8257536
constexpr long long BASE_OBJ  = BASE_WH * 2;              // 16515072
constexpr long long BASE_CLS  = BASE_OBJ + (long long)B * NSLOT; // 20643840
constexpr long long BASE_WT   = BASE_CLS + (long long)B * NSLOT; // 24772608
}

__device__ __forceinline__ int layer_offset(int l) {
    return l == 0 ? 0 : (l == 1 ? 49152 : 61440);
}

// Pass 2: ignore writes. One thread per (b, anchor, object).
// All writes store the same value (-1.0f) -> order-independent, fully parallel.
__global__ void ignore_kernel(const float* __restrict__ ious,
                              const float* __restrict__ gt_boxes,
                              float* __restrict__ out,
                              const int* __restrict__ in_h_p,
                              const int* __restrict__ in_w_p) {
    int idx = blockIdx.x * blockDim.x + threadIdx.x;
    if (idx >= B * A * O) return;
    float iou = ious[idx];                 // ious layout [B,A,O] flat == idx
    if (!(iou >= 0.5f)) return;

    int b = idx / (A * O);
    int r = idx - b * (A * O);
    int a = r / O;
    int o = r - a * O;

    const float* g = gt_boxes + ((long long)b * O + o) * 4;
    float xmin = g[0], ymin = g[1], xmax = g[2], ymax = g[3];
    float w = xmax - xmin, h = ymax - ymin;
    float gtx = (xmin + w) / 2.0f;
    float gty = (ymin + h) / 2.0f;
    bool valid = !((gtx == -1.0f) && (gty == -1.0f) && (w == 0.0f) && (h == 0.0f));
    if (!valid) return;

    int layer   = a / 3;
    int a_local = a - layer * 3;
    int fw = 128 >> layer;                 // fh == fw here
    int n_cells = fw * fw;

    float in_w = (float)in_w_p[0];
    float in_h = (float)in_h_p[0];
    float fx = gtx / in_w * (float)fw;
    float fy = gty / in_h * (float)fw;
    int loc_x = (int)fx;
    int loc_y = (int)fy;
    int cell = loc_y * fw + loc_x;
    if (cell < 0 || cell >= n_cells) return;   // JAX mode='drop'

    long long slot = (long long)layer_offset(layer) + (long long)cell * 3 + a_local;
    out[BASE_OBJ + (long long)b * NSLOT + slot] = -1.0f;
}

// Pass 3: matched writes. One thread per (b, layer); each loops o in order so
// duplicate (cell, a_loc) collisions resolve as last-object-wins, exactly like
// numpy fancy-index assignment. Collisions can only happen within one
// (b, layer) region, so threads never race with each other.
__global__ void match_kernel(const int*   __restrict__ matches,
                             const float* __restrict__ gt_boxes,
                             const int*   __restrict__ gt_ids,
                             const float* __restrict__ anc0,
                             const float* __restrict__ anc1,
                             const float* __restrict__ anc2,
                             float* __restrict__ out,
                             const int* __restrict__ in_h_p,
                             const int* __restrict__ in_w_p) {
    int b = threadIdx.x;        // 64 threads
    int layer = blockIdx.x;     // 3 blocks
    if (b >= B || layer >= 3) return;

    float in_w = (float)in_w_p[0];
    float in_h = (float)in_h_p[0];
    int fw = 128 >> layer;
    int n_cells = fw * fw;
    long long loff = layer_offset(layer);

    for (int o = 0; o < O; ++o) {
        int m = matches[b * O + o];
        if (m / 3 != layer) continue;          // matches >= a0 && < a1

        const float* g = gt_boxes + ((long long)b * O + o) * 4;
        float xmin = g[0], ymin = g[1], xmax = g[2], ymax = g[3];
        float w = xmax - xmin, h = ymax - ymin;
        float gtx = (xmin + w) / 2.0f;
        float gty = (ymin + h) / 2.0f;
        bool valid = !((gtx == -1.0f) && (gty == -1.0f) && (w == 0.0f) && (h == 0.0f));
        if (!valid) continue;

        float fx = gtx / in_w * (float)fw;
        float fy = gty / in_h * (float)fw;
        int loc_x = (int)fx;
        int loc_y = (int)fy;
        int cell = loc_y * fw + loc_x;
        if (cell < 0 || cell >= n_cells) continue;  // mode='drop'

        int a_loc = m - layer * 3;
        long long slot = loff + (long long)cell * 3 + a_loc;
        long long bs = (long long)b * NSLOT + slot;

        // matched anchor (global index m over concatenated anc0|anc1|anc2)
        const float* anc = (m < 3) ? anc0 : (m < 6) ? anc1 : anc2;
        int al = m % 3;
        float aw = anc[al * 2 + 0];
        float ah = anc[al * 2 + 1];

        float whx = logf(fmaxf(w, 1.0f) / aw);
        float why = logf(fmaxf(h, 1.0f) / ah);
        float wt  = 2.0f - w * h / in_w / in_h;
        float cls = (float)gt_ids[b * O + o];

        out[BASE_XCYC + bs * 2 + 0] = fx - (float)loc_x;
        out[BASE_XCYC + bs * 2 + 1] = fy - (float)loc_y;
        out[BASE_WH   + bs * 2 + 0] = whx;
        out[BASE_WH   + bs * 2 + 1] = why;
        out[BASE_WT   + bs * 2 + 0] = wt;
        out[BASE_WT   + bs * 2 + 1] = wt;
        out[BASE_OBJ  + bs] = 1.0f;            // overrides any -1 from ignore pass
        out[BASE_CLS  + bs] = cls;
    }
}

extern "C" void kernel_launch(void* const* d_in, const int* in_sizes, int n_in,
                              void* d_out, int out_size, void* d_ws, size_t ws_size,
                              hipStream_t stream) {
    const int*   matches  = (const int*)  d_in[0];
    const float* ious     = (const float*)d_in[1];
    // d_in[2..4] = out0/out1/out2 (shape-only, unused)
    const float* anc0     = (const float*)d_in[5];
    const float* anc1     = (const float*)d_in[6];
    const float* anc2     = (const float*)d_in[7];
    const float* gt_boxes = (const float*)d_in[8];
    const int*   gt_ids   = (const int*)  d_in[9];
    const int*   in_h_p   = (const int*)  d_in[10];
    const int*   in_w_p   = (const int*)  d_in[11];
    float* out = (float*)d_out;

    // Pass 1: zero the whole output (the memory-roofline term, ~132 MB writes).
    hipMemsetAsync(out, 0, (size_t)out_size * sizeof(float), stream);

    // Pass 2: ignore (-1.0) writes to obj.
    int n_ig = B * A * O;
    ignore_kernel<<<(n_ig + 255) / 256, 256, 0, stream>>>(ious, gt_boxes, out,
                                                          in_h_p, in_w_p);

    // Pass 3: matched writes (ordered per (b,layer) thread -> last-o-wins).
    match_kernel<<<3, 64, 0, stream>>>(matches, gt_boxes, gt_ids,
                                       anc0, anc1, anc2, out, in_h_p, in_w_p);
}

// Round 2
// 36.976 us; speedup vs baseline: 3.4798x; 3.4798x over previous
//
#include <hip/hip_runtime.h>

// Problem constants (fixed by setup_inputs):
//   B=64, O=100, A=9 anchors total (3 per layer)
//   layers: (128,128,3) (64,64,3) (32,32,3)
//   slots/layer: 49152, 12288, 3072  -> NSLOT = 64512 per batch
// Output (flat f32, concatenated in return order):
//   xcyc [B,NSLOT,2] | wh [B,NSLOT,2] | obj [B,NSLOT] | cls [B,NSLOT] | wt [B,NSLOT,2]

namespace {
constexpr int B = 64;
constexpr int O = 100;
constexpr int A = 9;
constexpr int NSLOT = 49152 + 12288 + 3072;               // 64512
constexpr long long BASE_XCYC = 0;
constexpr long long BASE_WH   = (long long)B * NSLOT * 2; // 8257536
constexpr long long BASE_OBJ  = BASE_WH * 2;              // 16515072
constexpr long long BASE_CLS  = BASE_OBJ + (long long)B * NSLOT; // 20643840
constexpr long long BASE_WT   = BASE_CLS + (long long)B * NSLOT; // 24772608
}

__device__ __forceinline__ int layer_offset(int l) {
    return l == 0 ? 0 : (l == 1 ? 49152 : 61440);
}

// Pass 2: ignore writes. One thread per (b, anchor, object).
// All writes store the same value (-1.0f) -> order-independent, fully parallel.
__global__ void ignore_kernel(const float* __restrict__ ious,
                              const float* __restrict__ gt_boxes,
                              float* __restrict__ out,
                              const int* __restrict__ in_h_p,
                              const int* __restrict__ in_w_p) {
    int idx = blockIdx.x * blockDim.x + threadIdx.x;
    if (idx >= B * A * O) return;
    float iou = ious[idx];                 // ious layout [B,A,O] flat == idx
    if (!(iou >= 0.5f)) return;

    int b = idx / (A * O);
    int r = idx - b * (A * O);
    int a = r / O;
    int o = r - a * O;

    const float* g = gt_boxes + ((long long)b * O + o) * 4;
    float xmin = g[0], ymin = g[1], xmax = g[2], ymax = g[3];
    float w = xmax - xmin, h = ymax - ymin;
    float gtx = (xmin + w) / 2.0f;
    float gty = (ymin + h) / 2.0f;
    bool valid = !((gtx == -1.0f) && (gty == -1.0f) && (w == 0.0f) && (h == 0.0f));
    if (!valid) return;

    int layer   = a / 3;
    int a_local = a - layer * 3;
    int fw = 128 >> layer;                 // fh == fw here
    int n_cells = fw * fw;

    float in_w = (float)in_w_p[0];
    float in_h = (float)in_h_p[0];
    float fx = gtx / in_w * (float)fw;
    float fy = gty / in_h * (float)fw;
    int loc_x = (int)fx;
    int loc_y = (int)fy;
    int cell = loc_y * fw + loc_x;
    if (cell < 0 || cell >= n_cells) return;   // JAX mode='drop'

    long long slot = (long long)layer_offset(layer) + (long long)cell * 3 + a_local;
    out[BASE_OBJ + (long long)b * NSLOT + slot] = -1.0f;
}

// Pass 3: matched writes, fully parallel with last-index-wins semantics.
// One block per batch b, one thread per object o. Each thread computes its
// object's global per-batch slot (layer_offset + cell*3 + a_loc; unique
// encoding, so cross-layer collisions impossible). Slots go to LDS; after a
// barrier each thread suppresses its writes if ANY LATER object maps to the
// same slot -> exact numpy fancy-assignment last-wins, but parallel.
__global__ void match_kernel(const int*   __restrict__ matches,
                             const float* __restrict__ gt_boxes,
                             const int*   __restrict__ gt_ids,
                             const float* __restrict__ anc0,
                             const float* __restrict__ anc1,
                             const float* __restrict__ anc2,
                             float* __restrict__ out,
                             const int* __restrict__ in_h_p,
                             const int* __restrict__ in_w_p) {
    __shared__ int slots[O];

    int b = blockIdx.x;
    int o = threadIdx.x;

    float in_w = (float)in_w_p[0];
    float in_h = (float)in_h_p[0];

    int   slot = -1;
    float fx = 0.f, fy = 0.f, w = 0.f, h = 0.f;
    int   loc_x = 0, loc_y = 0, m = 0;

    if (o < O) {
        m = matches[b * O + o];
        int layer = m / 3;                  // m in [0,9)
        int fw = 128 >> layer;
        int n_cells = fw * fw;

        const float* g = gt_boxes + ((long long)b * O + o) * 4;
        float xmin = g[0], ymin = g[1], xmax = g[2], ymax = g[3];
        w = xmax - xmin;
        h = ymax - ymin;
        float gtx = (xmin + w) / 2.0f;
        float gty = (ymin + h) / 2.0f;
        bool valid = !((gtx == -1.0f) && (gty == -1.0f) && (w == 0.0f) && (h == 0.0f));

        if (valid) {
            fx = gtx / in_w * (float)fw;
            fy = gty / in_h * (float)fw;
            loc_x = (int)fx;
            loc_y = (int)fy;
            int cell = loc_y * fw + loc_x;
            if (cell >= 0 && cell < n_cells) {      // JAX mode='drop'
                int a_loc = m - layer * 3;
                slot = layer_offset(layer) + cell * 3 + a_loc;
            }
        }
        slots[o] = slot;
    }
    __syncthreads();

    if (o >= O || slot < 0) return;

    // last-index-wins: skip if any later object hits the same slot
    for (int o2 = o + 1; o2 < O; ++o2) {
        if (slots[o2] == slot) return;
    }

    long long bs = (long long)b * NSLOT + slot;

    const float* anc = (m < 3) ? anc0 : (m < 6) ? anc1 : anc2;
    int al = m % 3;
    float aw = anc[al * 2 + 0];
    float ah = anc[al * 2 + 1];

    float whx = logf(fmaxf(w, 1.0f) / aw);
    float why = logf(fmaxf(h, 1.0f) / ah);
    float wt  = 2.0f - w * h / in_w / in_h;
    float cls = (float)gt_ids[b * O + o];

    out[BASE_XCYC + bs * 2 + 0] = fx - (float)loc_x;
    out[BASE_XCYC + bs * 2 + 1] = fy - (float)loc_y;
    out[BASE_WH   + bs * 2 + 0] = whx;
    out[BASE_WH   + bs * 2 + 1] = why;
    out[BASE_WT   + bs * 2 + 0] = wt;
    out[BASE_WT   + bs * 2 + 1] = wt;
    out[BASE_OBJ  + bs] = 1.0f;            // overrides any -1 from ignore pass
    out[BASE_CLS  + bs] = cls;
}

extern "C" void kernel_launch(void* const* d_in, const int* in_sizes, int n_in,
                              void* d_out, int out_size, void* d_ws, size_t ws_size,
                              hipStream_t stream) {
    const int*   matches  = (const int*)  d_in[0];
    const float* ious     = (const float*)d_in[1];
    // d_in[2..4] = out0/out1/out2 (shape-only, unused)
    const float* anc0     = (const float*)d_in[5];
    const float* anc1     = (const float*)d_in[6];
    const float* anc2     = (const float*)d_in[7];
    const float* gt_boxes = (const float*)d_in[8];
    const int*   gt_ids   = (const int*)  d_in[9];
    const int*   in_h_p   = (const int*)  d_in[10];
    const int*   in_w_p   = (const int*)  d_in[11];
    float* out = (float*)d_out;

    // Pass 1: zero the whole output (the memory-roofline term, ~132 MB writes).
    hipMemsetAsync(out, 0, (size_t)out_size * sizeof(float), stream);

    // Pass 2: ignore (-1.0) writes to obj.
    int n_ig = B * A * O;
    ignore_kernel<<<(n_ig + 255) / 256, 256, 0, stream>>>(ious, gt_boxes, out,
                                                          in_h_p, in_w_p);

    // Pass 3: matched writes (parallel, LDS-mediated last-wins).
    match_kernel<<<B, 128, 0, stream>>>(matches, gt_boxes, gt_ids,
                                        anc0, anc1, anc2, out, in_h_p, in_w_p);
}

// Round 3
// 32.901 us; speedup vs baseline: 3.9108x; 1.1239x over previous
//
#include <hip/hip_runtime.h>

// Fused YOLO target encoder — single kernel.
//   B=64, O=100, A=9 (3 per layer); layers (128,128,3),(64,64,3),(32,32,3)
//   NSLOT = 49152+12288+3072 = 64512 slots per batch
// Output (flat f32): xcyc[B,NSLOT,2] | wh[B,NSLOT,2] | obj[B,NSLOT] | cls[B,NSLOT] | wt[B,NSLOT,2]
//
// Partition: 1024 blocks = 64 batches x 16 sub-chunks. Sub-chunk r of batch b
// owns slots [r*4032, (r+1)*4032) across ALL five segments — every float of a
// record with slot s belongs to sub-chunk s/4032, so each block can zero its
// chunk and then apply exactly its own records with no cross-block races.

namespace {
constexpr int B = 64;
constexpr int O = 100;
constexpr int A = 9;
constexpr int NSLOT = 64512;
constexpr int SUB = 16;                       // sub-chunks per batch
constexpr int SLOT_PER_SUB = NSLOT / SUB;     // 4032
constexpr long long BASE_XCYC = 0;
constexpr long long BASE_WH   = (long long)B * NSLOT * 2;        // 8257536
constexpr long long BASE_OBJ  = BASE_WH * 2;                     // 16515072
constexpr long long BASE_CLS  = BASE_OBJ + (long long)B * NSLOT; // 20643840
constexpr long long BASE_WT   = BASE_CLS + (long long)B * NSLOT; // 24772608
}

__device__ __forceinline__ int layer_offset(int l) {
    return l == 0 ? 0 : (l == 1 ? 49152 : 61440);
}

__global__ __launch_bounds__(256) void encode_fused(
        const int*   __restrict__ matches,
        const float* __restrict__ ious,
        const float* __restrict__ anc0,
        const float* __restrict__ anc1,
        const float* __restrict__ anc2,
        const float* __restrict__ gt_boxes,
        const int*   __restrict__ gt_ids,
        float*       __restrict__ out,
        const int*   __restrict__ in_h_p,
        const int*   __restrict__ in_w_p) {
    __shared__ int   m_slot[O];        // matched slot per object (-1 = none)
    __shared__ float m_val[O][6];      // fx-lx, fy-ly, whx, why, wt, cls
    __shared__ int   ig_slot[A * O];   // ignore slot per (a,o) (-1 = none)

    const int blk = blockIdx.x;
    const int b = blk >> 4;            // batch
    const int r = blk & (SUB - 1);     // sub-chunk
    const int t = threadIdx.x;

    const float in_w = (float)in_w_p[0];
    const float in_h = (float)in_h_p[0];

    // ---- match records (threads 0..O-1), redundantly per sub-chunk ----
    if (t < O) {
        int m = matches[b * O + t];                // m in [0,9)
        const float* g = gt_boxes + ((long long)b * O + t) * 4;
        float xmin = g[0], ymin = g[1], xmax = g[2], ymax = g[3];
        float w = xmax - xmin, h = ymax - ymin;
        float gtx = (xmin + w) * 0.5f, gty = (ymin + h) * 0.5f;
        bool valid = !((gtx == -1.0f) && (gty == -1.0f) && (w == 0.0f) && (h == 0.0f));

        int layer = m / 3;
        int fw = 128 >> layer;
        int slot = -1;
        float fxr = 0.f, fyr = 0.f, whx = 0.f, why = 0.f, wt = 0.f, cls = 0.f;
        if (valid) {
            float fx = gtx / in_w * (float)fw;
            float fy = gty / in_h * (float)fw;
            int lx = (int)fx, ly = (int)fy;
            int cell = ly * fw + lx;
            if (cell >= 0 && cell < fw * fw) {     // JAX mode='drop'
                slot = layer_offset(layer) + cell * 3 + (m - layer * 3);
                const float* anc = (m < 3) ? anc0 : (m < 6) ? anc1 : anc2;
                int al = m % 3;
                whx = logf(fmaxf(w, 1.0f) / anc[al * 2 + 0]);
                why = logf(fmaxf(h, 1.0f) / anc[al * 2 + 1]);
                wt  = 2.0f - w * h / in_w / in_h;
                cls = (float)gt_ids[b * O + t];
                fxr = fx - (float)lx;
                fyr = fy - (float)ly;
            }
        }
        m_slot[t] = slot;
        m_val[t][0] = fxr; m_val[t][1] = fyr;
        m_val[t][2] = whx; m_val[t][3] = why;
        m_val[t][4] = wt;  m_val[t][5] = cls;
    }

    // ---- ignore records: 900 (a,o) pairs over 256 threads ----
    for (int idx = t; idx < A * O; idx += 256) {
        int a = idx / O;
        int o = idx - a * O;
        float iou = ious[((long long)b * A + a) * O + o];
        int slot = -1;
        if (iou >= 0.5f) {
            const float* g = gt_boxes + ((long long)b * O + o) * 4;
            float xmin = g[0], ymin = g[1], xmax = g[2], ymax = g[3];
            float w = xmax - xmin, h = ymax - ymin;
            float gtx = (xmin + w) * 0.5f, gty = (ymin + h) * 0.5f;
            bool valid = !((gtx == -1.0f) && (gty == -1.0f) && (w == 0.0f) && (h == 0.0f));
            if (valid) {
                int layer = a / 3;
                int fw = 128 >> layer;
                float fx = gtx / in_w * (float)fw;
                float fy = gty / in_h * (float)fw;
                int lx = (int)fx, ly = (int)fy;
                int cell = ly * fw + lx;
                if (cell >= 0 && cell < fw * fw)
                    slot = layer_offset(layer) + cell * 3 + (a - layer * 3);
            }
        }
        ig_slot[idx] = slot;
    }

    // ---- zero this block's chunk (float4 streaming stores) ----
    // Per sub-chunk: xcyc/wh/wt = 8064 floats (2016 f4) each; obj/cls = 4032 (1008 f4).
    const long long fx_base = ((long long)b * NSLOT + (long long)r * SLOT_PER_SUB) * 2;
    const long long s_base  =  (long long)b * NSLOT + (long long)r * SLOT_PER_SUB;
    float4* p_xcyc = (float4*)(out + BASE_XCYC + fx_base);
    float4* p_wh   = (float4*)(out + BASE_WH   + fx_base);
    float4* p_wt   = (float4*)(out + BASE_WT   + fx_base);
    float4* p_obj  = (float4*)(out + BASE_OBJ  + s_base);
    float4* p_cls  = (float4*)(out + BASE_CLS  + s_base);
    const float4 z = make_float4(0.f, 0.f, 0.f, 0.f);
    constexpr int F4_BIG = SLOT_PER_SUB * 2 / 4;   // 2016
    constexpr int F4_SMALL = SLOT_PER_SUB / 4;     // 1008
    for (int i = t; i < F4_BIG; i += 256) { p_xcyc[i] = z; p_wh[i] = z; p_wt[i] = z; }
    for (int i = t; i < F4_SMALL; i += 256) { p_obj[i] = z; p_cls[i] = z; }

    __syncthreads();   // zeros + LDS records visible block-wide

    // ---- ignore pokes (obj = -1.0), only slots this block owns ----
    const int slot_lo = r * SLOT_PER_SUB;
    const int slot_hi = slot_lo + SLOT_PER_SUB;
    for (int idx = t; idx < A * O; idx += 256) {
        int s = ig_slot[idx];
        if (s >= slot_lo && s < slot_hi)
            out[BASE_OBJ + (long long)b * NSLOT + s] = -1.0f;
    }

    __syncthreads();   // ignore writes land before match overrides

    // ---- match pokes, numpy last-index-wins ----
    if (t < O) {
        int s = m_slot[t];
        if (s >= slot_lo && s < slot_hi) {
            bool superseded = false;
            for (int o2 = t + 1; o2 < O; ++o2)
                if (m_slot[o2] == s) { superseded = true; break; }
            if (!superseded) {
                long long bs = (long long)b * NSLOT + s;
                out[BASE_XCYC + bs * 2 + 0] = m_val[t][0];
                out[BASE_XCYC + bs * 2 + 1] = m_val[t][1];
                out[BASE_WH   + bs * 2 + 0] = m_val[t][2];
                out[BASE_WH   + bs * 2 + 1] = m_val[t][3];
                out[BASE_WT   + bs * 2 + 0] = m_val[t][4];
                out[BASE_WT   + bs * 2 + 1] = m_val[t][4];
                out[BASE_OBJ  + bs] = 1.0f;
                out[BASE_CLS  + bs] = m_val[t][5];
            }
        }
    }
}

extern "C" void kernel_launch(void* const* d_in, const int* in_sizes, int n_in,
                              void* d_out, int out_size, void* d_ws, size_t ws_size,
                              hipStream_t stream) {
    const int*   matches  = (const int*)  d_in[0];
    const float* ious     = (const float*)d_in[1];
    // d_in[2..4] = out0/out1/out2 (shape-only, unused)
    const float* anc0     = (const float*)d_in[5];
    const float* anc1     = (const float*)d_in[6];
    const float* anc2     = (const float*)d_in[7];
    const float* gt_boxes = (const float*)d_in[8];
    const int*   gt_ids   = (const int*)  d_in[9];
    const int*   in_h_p   = (const int*)  d_in[10];
    const int*   in_w_p   = (const int*)  d_in[11];
    float* out = (float*)d_out;

    encode_fused<<<B * SUB, 256, 0, stream>>>(matches, ious, anc0, anc1, anc2,
                                              gt_boxes, gt_ids, out, in_h_p, in_w_p);
}